// Round 10
// baseline (181.367 us; speedup 1.0000x reference)
//
#include <hip/hip_runtime.h>
#include <math.h>

// ---- model constants (match reference) ----
#define C_DT_OVER_SOMA  500000.0f      // DT / 2e-10
#define C_DT_OVER_AIS   1000000.0f     // DT / 1e-10
#define C_SOMA_GL       1e-8f
#define C_SOMA_EL       (-0.070f)
#define C_AIS_GL        1e-8f
#define C_AIS_EL        (-0.070f)
#define C_V_T           (-0.050f)
#define C_DELTA_T       0.002f
#define C_V_SPIKE       (-0.030f)
#define C_V_RESET       (-0.065f)
#define C_G_C           5e-9f
#define C_G_MAX         1e-9f
#define C_DECAY_G       0.9801986733067553f   // exp(-DT/0.005)
#define C_DECAY_TR      0.9950124791926823f   // exp(-DT/0.020)
#define C_DECAY_RATE    0.9990004998333751f   // exp(-DT/0.100)
#define C_DT_TAU_THETA  1e-4f
#define C_A_PLUS        0.01f
#define C_A_MINUS       0.012f
#define C_ETA_BCM       1e-4f

#define TILE_BITS   15
#define TILE_SIZE   32768               // neurons per tile (128 KB LDS accumulator)
#define TILE_MASK   (TILE_SIZE - 1)
#define NTILES      8                   // N / TILE_SIZE
#define KCHUNK      32                  // chunk-blocks per tile
#define RING_BPR    256                 // blocks per ring row
#define NBW         8192                // bitmask words (N/32)

typedef float fx4 __attribute__((ext_vector_type(4)));
typedef int   ix4 __attribute__((ext_vector_type(4)));
typedef unsigned char uchar;

__device__ __forceinline__ fx4 nt_load4(const float* p) {
    return __builtin_nontemporal_load((const fx4*)p);
}
__device__ __forceinline__ ix4 nt_loadi4(const int* p) {
    return __builtin_nontemporal_load((const ix4*)p);
}
__device__ __forceinline__ float nt_loadf(const float* p) {
    return __builtin_nontemporal_load(p);
}
__device__ __forceinline__ void nt_store4(float* p, fx4 v) {
    __builtin_nontemporal_store(v, (fx4*)p);
}

__global__ void k_zero4(float4* __restrict__ p, int n4) {
    int i = blockIdx.x * blockDim.x + threadIdx.x;
    if (i < n4) p[i] = make_float4(0.f, 0.f, 0.f, 0.f);
}

// Tiled scatter: block (t,k) accumulates chunk k's synapses targeting tile t
// into a 128 KB LDS accumulator, then writes its partial.
// Block mapping t=bid>>5, k=bid&31: with round-robin XCD dispatch and
// 1 block/CU, each XCD's 32 co-resident blocks cover only 4 distinct chunks,
// each read by 8 same-XCD blocks in lockstep -> chunk stream served from L2.
__global__ void __launch_bounds__(512, 1)
k_scatter_tile(const float4* __restrict__ g4,
               const float4* __restrict__ w4,
               const int4*   __restrict__ post4,
               float*        __restrict__ partials,   // [NTILES*KCHUNK][TILE_SIZE]
               int S) {
    extern __shared__ float acc[];                    // TILE_SIZE floats
    const int t = blockIdx.x >> 5;                    // tile
    const int k = blockIdx.x & 31;                    // chunk

    for (int i = threadIdx.x; i < TILE_SIZE; i += blockDim.x)
        acc[i] = 0.0f;
    __syncthreads();

    const int cnt4  = (S / KCHUNK) / 4;               // float4 groups per chunk
    const int base4 = k * cnt4;
    for (int j = threadIdx.x; j < cnt4; j += blockDim.x) {
        int4   p = post4[base4 + j];
        float4 g = g4[base4 + j];
        float4 w = w4[base4 + j];
        if ((p.x >> TILE_BITS) == t) atomicAdd(&acc[p.x & TILE_MASK], g.x * w.x);
        if ((p.y >> TILE_BITS) == t) atomicAdd(&acc[p.y & TILE_MASK], g.y * w.y);
        if ((p.z >> TILE_BITS) == t) atomicAdd(&acc[p.z & TILE_MASK], g.z * w.z);
        if ((p.w >> TILE_BITS) == t) atomicAdd(&acc[p.w & TILE_MASK], g.w * w.w);
    }
    __syncthreads();

    // partials written once, read once by k_neuron soon after -> cacheable
    float* dst = partials + ((size_t)t * KCHUNK + k) * TILE_SIZE;
    const float4* src = (const float4*)acc;
    for (int i = threadIdx.x; i < TILE_SIZE / 4; i += blockDim.x)
        ((float4*)dst)[i] = src[i];
}

// neuron step; fast path sums KCHUNK partials for its tile, fallback reads A[i]
template <bool FAST>
__global__ void k_neuron(const float* __restrict__ ext,
                         const float* __restrict__ Vs,
                         const float* __restrict__ Va,
                         const float* __restrict__ refrac,
                         const float* __restrict__ A,
                         float* __restrict__ spikes,
                         float* __restrict__ Vs_out,
                         float* __restrict__ Va_out,
                         int N) {
    int i = blockIdx.x * blockDim.x + threadIdx.x;
    if (i >= N) return;
    float acc = 0.0f;
    if (FAST) {
        const int t = i >> TILE_BITS;
        const int local = i & TILE_MASK;
        const float* base = A + ((size_t)t * KCHUNK) * TILE_SIZE + local;
        #pragma unroll
        for (int k = 0; k < KCHUNK; ++k) acc += nt_loadf(base + (size_t)k * TILE_SIZE);
    } else {
        acc = A[i];
    }
    float vs = Vs[i];
    float va = Va[i];
    float I_syn = C_G_MAX * (0.0f - vs) * acc;   // E_REV = 0
    float dvs = C_DT_OVER_SOMA * (-C_SOMA_GL * (vs - C_SOMA_EL) + ext[i]
                                  + I_syn + C_G_C * (va - vs));
    float xarg = fminf((va - C_V_T) / C_DELTA_T, 20.0f);
    float exp_term = C_AIS_GL * C_DELTA_T * expf(xarg);
    float dva = C_DT_OVER_AIS * (-C_AIS_GL * (va - C_AIS_EL) + exp_term
                                 + C_G_C * (vs - va));
    float vs_new = vs + dvs;
    float va_new = (0.0f < refrac[i]) ? C_V_RESET : (va + dva);
    float hard = (va_new >= C_V_SPIKE) ? 1.0f : 0.0f;
    float va_out = (hard > 0.0f) ? C_V_RESET : va_new;
    spikes[i] = hard;          // gathered next -> keep cacheable
    __builtin_nontemporal_store(vs_new, &Vs_out[i]);
    __builtin_nontemporal_store(va_out, &Va_out[i]);
}

// pack spikes into a 32 KB bitmask
__global__ void k_bits(const float* __restrict__ spikes,
                       unsigned long long* __restrict__ bits,
                       int N) {
    int i = blockIdx.x * blockDim.x + threadIdx.x;
    if (i >= N) return;
    float s = spikes[i];
    unsigned long long m = __ballot(s > 0.5f);
    if ((threadIdx.x & 63) == 0) bits[i >> 6] = m;
}

// fallback scatter (device-scope HW fp atomics)
__global__ void k_scatter_gw_dev(const float4* __restrict__ g4,
                                 const float4* __restrict__ w4,
                                 const int4*   __restrict__ post4,
                                 float*        __restrict__ A,
                                 int S4) {
    int t = blockIdx.x * blockDim.x + threadIdx.x;
    if (t >= S4) return;
    float4 g = g4[t];
    float4 w = w4[t];
    int4   p = post4[t];
    unsafeAtomicAdd(&A[p.x], g.x * w.x);
    unsafeAtomicAdd(&A[p.y], g.y * w.y);
    unsafeAtomicAdd(&A[p.z], g.z * w.z);
    unsafeAtomicAdd(&A[p.w], g.w * w.w);
}

// plasticity (STDP + BCM -> w_out) + prerow; spike bitmask staged in LDS,
// all single-use streams via nt loads (keep L1/L2 for the bitmask + prerow).
__global__ void k_plast_bits(const float* __restrict__ syn_w,
                             const float* __restrict__ pre_trace,
                             const float* __restrict__ post_trace,
                             const float* __restrict__ r_pre,
                             const float* __restrict__ r_post,
                             const float* __restrict__ theta_m,
                             const int*   __restrict__ pre_idx,
                             const int*   __restrict__ post_idx,
                             const int*   __restrict__ delay,
                             const int*   __restrict__ bidx_p,
                             const unsigned* __restrict__ bits32,
                             float* __restrict__ w_out,
                             uchar* __restrict__ prerow,
                             int S) {
    __shared__ unsigned sb[NBW];                       // 32 KB spike bitmask
    for (int i = threadIdx.x; i < NBW; i += blockDim.x)
        sb[i] = bits32[i];
    __syncthreads();

    int t = blockIdx.x * blockDim.x + threadIdx.x;
    int j = t * 8;
    if (j >= S) return;
    const int bidx = bidx_p[0];

    ix4 pi0 = nt_loadi4(pre_idx + j);
    ix4 pi1 = nt_loadi4(pre_idx + j + 4);
    ix4 qi0 = nt_loadi4(post_idx + j);
    ix4 qi1 = nt_loadi4(post_idx + j + 4);
    ix4 dl0 = nt_loadi4(delay + j);
    ix4 dl1 = nt_loadi4(delay + j + 4);

    int piv[8] = {pi0.x, pi0.y, pi0.z, pi0.w, pi1.x, pi1.y, pi1.z, pi1.w};
    int qiv[8] = {qi0.x, qi0.y, qi0.z, qi0.w, qi1.x, qi1.y, qi1.z, qi1.w};
    int dlv[8] = {dl0.x, dl0.y, dl0.z, dl0.w, dl1.x, dl1.y, dl1.z, dl1.w};

    float pre[8], post[8];
    #pragma unroll
    for (int k = 0; k < 8; ++k) {
        pre[k]  = (float)((sb[piv[k] >> 5] >> (piv[k] & 31)) & 1u);
        post[k] = (float)((sb[qiv[k] >> 5] >> (qiv[k] & 31)) & 1u);
    }

    fx4 w0  = nt_load4(syn_w + j);
    fx4 w1  = nt_load4(syn_w + j + 4);
    fx4 pt0 = nt_load4(pre_trace + j);
    fx4 pt1 = nt_load4(pre_trace + j + 4);
    fx4 qt0 = nt_load4(post_trace + j);
    fx4 qt1 = nt_load4(post_trace + j + 4);
    fx4 rp0 = nt_load4(r_pre + j);
    fx4 rp1 = nt_load4(r_pre + j + 4);
    fx4 rq0 = nt_load4(r_post + j);
    fx4 rq1 = nt_load4(r_post + j + 4);
    fx4 th0 = nt_load4(theta_m + j);
    fx4 th1 = nt_load4(theta_m + j + 4);

    float wv[8]  = {w0.x, w0.y, w0.z, w0.w, w1.x, w1.y, w1.z, w1.w};
    float ptv[8] = {pt0.x, pt0.y, pt0.z, pt0.w, pt1.x, pt1.y, pt1.z, pt1.w};
    float qtv[8] = {qt0.x, qt0.y, qt0.z, qt0.w, qt1.x, qt1.y, qt1.z, qt1.w};
    float rpv[8] = {rp0.x, rp0.y, rp0.z, rp0.w, rp1.x, rp1.y, rp1.z, rp1.w};
    float rqv[8] = {rq0.x, rq0.y, rq0.z, rq0.w, rq1.x, rq1.y, rq1.z, rq1.w};
    float thv[8] = {th0.x, th0.y, th0.z, th0.w, th1.x, th1.y, th1.z, th1.w};

    float wo[8];
    unsigned prw[8];
    #pragma unroll
    for (int k = 0; k < 8; ++k) {
        float ptr_n = ptv[k] * C_DECAY_TR + pre[k];
        float qtr_n = qtv[k] * C_DECAY_TR + post[k];
        float dw_stdp = C_A_PLUS * ptr_n * post[k] - C_A_MINUS * qtr_n * pre[k];
        float rpn = rpv[k] * C_DECAY_RATE + pre[k];
        float rqn = rqv[k] * C_DECAY_RATE + post[k];
        float thn = thv[k] + C_DT_TAU_THETA * (rqn * rqn - thv[k]);
        float dw_bcm = C_ETA_BCM * rpn * rqn * (rqn - thn);
        float wn = wv[k] + dw_stdp + dw_bcm;
        wo[k] = fminf(fmaxf(wn, 0.0f), 1.0f);
        prw[k] = (pre[k] > 0.5f) ? (unsigned)(((bidx + dlv[k]) & 7) + 1) : 0u;
    }
    fx4 a = {wo[0], wo[1], wo[2], wo[3]};
    fx4 b = {wo[4], wo[5], wo[6], wo[7]};
    nt_store4(w_out + j, a);
    nt_store4(w_out + j + 4, b);

    uint2 packed;
    packed.x = prw[0] | (prw[1] << 8) | (prw[2] << 16) | (prw[3] << 24);
    packed.y = prw[4] | (prw[5] << 8) | (prw[6] << 16) | (prw[7] << 24);
    *(uint2*)(prerow + j) = packed;     // cacheable: re-read 8x by ring pass
}

// ring pass, lane-contiguous: 8 rows x RING_BPR blocks; one float4 per thread
// per iteration (1 KB contiguous per wave instruction).
__global__ void k_ring_row(const float* __restrict__ gbuf,
                           const float* __restrict__ syn_g,
                           const uchar* __restrict__ prerow,
                           const int*   __restrict__ bidx_p,
                           float* __restrict__ g_out,
                           float* __restrict__ buf_out,
                           int S) {
    const int bidx = bidx_p[0];
    const int row  = blockIdx.x / RING_BPR;
    const int blk  = blockIdx.x - row * RING_BPR;
    const int span = S / RING_BPR;
    const int base = blk * span;
    const float* src = gbuf + (size_t)row * (size_t)S;
    float*       dst = buf_out + (size_t)row * (size_t)S;
    const unsigned target = (unsigned)(row + 1);
    const int step = blockDim.x * 4;

    if (row == bidx) {
        for (int off = threadIdx.x * 4; off < span; off += step) {
            const int j = base + off;
            fx4 v  = nt_load4(src + j);
            fx4 sg = nt_load4(syn_g + j);      // L3-hot from scatter pass
            fx4 go = sg * (float)C_DECAY_G + v;
            nt_store4(g_out + j, go);
            unsigned wd = *(const unsigned*)(prerow + j);
            fx4 z;
            z.x = ((wd        & 255u) == target) ? 1.0f : 0.0f;
            z.y = (((wd >> 8)  & 255u) == target) ? 1.0f : 0.0f;
            z.z = (((wd >> 16) & 255u) == target) ? 1.0f : 0.0f;
            z.w = (((wd >> 24)       ) == target) ? 1.0f : 0.0f;
            nt_store4(dst + j, z);
        }
    } else {
        for (int off = threadIdx.x * 4; off < span; off += step) {
            const int j = base + off;
            fx4 v = nt_load4(src + j);
            unsigned wd = *(const unsigned*)(prerow + j);
            v.x += ((wd        & 255u) == target) ? 1.0f : 0.0f;
            v.y += (((wd >> 8)  & 255u) == target) ? 1.0f : 0.0f;
            v.z += (((wd >> 16) & 255u) == target) ? 1.0f : 0.0f;
            v.w += (((wd >> 24)       ) == target) ? 1.0f : 0.0f;
            nt_store4(dst + j, v);
        }
    }
}

// fallback fused per-synapse update (arbitrary L)
__global__ void k_syn_update4(const float* __restrict__ syn_g,
                              const float* __restrict__ syn_w,
                              const float* __restrict__ pre_trace,
                              const float* __restrict__ post_trace,
                              const float* __restrict__ r_pre,
                              const float* __restrict__ r_post,
                              const float* __restrict__ theta_m,
                              const float* __restrict__ gbuf,
                              const int*   __restrict__ pre_idx,
                              const int*   __restrict__ post_idx,
                              const int*   __restrict__ delay,
                              const int*   __restrict__ bidx_p,
                              const float* __restrict__ spikes,
                              float* __restrict__ g_out,
                              float* __restrict__ w_out,
                              float* __restrict__ buf_out,
                              int S, int L) {
    int t = blockIdx.x * blockDim.x + threadIdx.x;
    int j = t * 4;
    if (j >= S) return;
    const int bidx = bidx_p[0];
    int4 pi = *(const int4*)(pre_idx + j);
    int4 qi = *(const int4*)(post_idx + j);
    int4 dl = *(const int4*)(delay + j);
    float pre[4], post[4];
    pre[0] = spikes[pi.x]; pre[1] = spikes[pi.y]; pre[2] = spikes[pi.z]; pre[3] = spikes[pi.w];
    post[0] = spikes[qi.x]; post[1] = spikes[qi.y]; post[2] = spikes[qi.z]; post[3] = spikes[qi.w];
    float4 g  = *(const float4*)(syn_g + j);
    float4 w  = *(const float4*)(syn_w + j);
    float4 pt = *(const float4*)(pre_trace + j);
    float4 qt = *(const float4*)(post_trace + j);
    float4 rp = *(const float4*)(r_pre + j);
    float4 rq = *(const float4*)(r_post + j);
    float4 th = *(const float4*)(theta_m + j);
    float wv[4]  = {w.x, w.y, w.z, w.w};
    float ptv[4] = {pt.x, pt.y, pt.z, pt.w};
    float qtv[4] = {qt.x, qt.y, qt.z, qt.w};
    float rpv[4] = {rp.x, rp.y, rp.z, rp.w};
    float rqv[4] = {rq.x, rq.y, rq.z, rq.w};
    float thv[4] = {th.x, th.y, th.z, th.w};
    float wo[4];
    #pragma unroll
    for (int k = 0; k < 4; ++k) {
        float ptr_n = ptv[k] * C_DECAY_TR + pre[k];
        float qtr_n = qtv[k] * C_DECAY_TR + post[k];
        float dw_stdp = C_A_PLUS * ptr_n * post[k] - C_A_MINUS * qtr_n * pre[k];
        float rpn = rpv[k] * C_DECAY_RATE + pre[k];
        float rqn = rqv[k] * C_DECAY_RATE + post[k];
        float thn = thv[k] + C_DT_TAU_THETA * (rqn * rqn - thv[k]);
        float dw_bcm = C_ETA_BCM * rpn * rqn * (rqn - thn);
        float wn = wv[k] + dw_stdp + dw_bcm;
        wo[k] = fminf(fmaxf(wn, 0.0f), 1.0f);
    }
    float4 wo4 = {wo[0], wo[1], wo[2], wo[3]};
    *(float4*)(w_out + j) = wo4;
    int row[4];
    row[0] = (bidx + dl.x) % L;
    row[1] = (bidx + dl.y) % L;
    row[2] = (bidx + dl.z) % L;
    row[3] = (bidx + dl.w) % L;
    float gv[4] = {g.x, g.y, g.z, g.w};
    for (int r = 0; r < L; ++r) {
        float4 v = *(const float4*)(gbuf + (size_t)r * (size_t)S + j);
        float vv[4] = {v.x, v.y, v.z, v.w};
        if (r == bidx) {
            float4 gn;
            gn.x = gv[0] * C_DECAY_G + vv[0];
            gn.y = gv[1] * C_DECAY_G + vv[1];
            gn.z = gv[2] * C_DECAY_G + vv[2];
            gn.w = gv[3] * C_DECAY_G + vv[3];
            *(float4*)(g_out + j) = gn;
            vv[0] = vv[1] = vv[2] = vv[3] = 0.0f;
        }
        #pragma unroll
        for (int k = 0; k < 4; ++k)
            if (r == row[k]) vv[k] += pre[k];
        float4 ov = {vv[0], vv[1], vv[2], vv[3]};
        *(float4*)(buf_out + (size_t)r * (size_t)S + j) = ov;
    }
}

extern "C" void kernel_launch(void* const* d_in, const int* in_sizes, int n_in,
                              void* d_out, int out_size, void* d_ws, size_t ws_size,
                              hipStream_t stream) {
    const int N = in_sizes[0];
    const int S = in_sizes[1];
    const int L = in_sizes[11] / S;

    const float* ext        = (const float*)d_in[0];
    const float* syn_w      = (const float*)d_in[1];
    const float* Vs         = (const float*)d_in[2];
    const float* Va         = (const float*)d_in[3];
    const float* refrac     = (const float*)d_in[4];
    const float* syn_g      = (const float*)d_in[5];
    const float* pre_trace  = (const float*)d_in[6];
    const float* post_trace = (const float*)d_in[7];
    const float* r_pre      = (const float*)d_in[8];
    const float* r_post     = (const float*)d_in[9];
    const float* theta_m    = (const float*)d_in[10];
    const float* gbuf       = (const float*)d_in[11];
    const int*   pre_idx    = (const int*)d_in[12];
    const int*   post_idx   = (const int*)d_in[13];
    const int*   delay      = (const int*)d_in[14];
    const int*   bidx       = (const int*)d_in[15];

    float* out     = (float*)d_out;
    float* spikes  = out;
    float* Vs_out  = out + (size_t)N;
    float* Va_out  = out + (size_t)2 * N;
    float* g_out   = out + (size_t)3 * N;
    float* w_out   = out + (size_t)3 * N + (size_t)S;
    float* buf_out = out + (size_t)3 * N + (size_t)2 * S;

    // ws layout: A partials [0, 32MB); prerow aliases A[0, S) (written after A
    // is dead); bits alias A at +8MB (written after A is dead, clear of prerow).
    float* A = (float*)d_ws;
    uchar* prerow = (uchar*)d_ws;
    unsigned long long* bits = (unsigned long long*)((char*)d_ws + ((size_t)8 << 20));

    const size_t need = (size_t)NTILES * KCHUNK * TILE_SIZE * sizeof(float);
    const bool fastScatter = (N == NTILES * TILE_SIZE) &&
                             (S % (KCHUNK * 4) == 0) &&
                             (ws_size >= need);
    const bool fastSyn = fastScatter && (L == 8) && (S % (RING_BPR * 256 * 4) == 0) &&
                         (S % 8 == 0) && (N % 256 == 0) &&
                         (((size_t)8 << 20) + N / 8 <= ws_size) && ((size_t)S <= ((size_t)8 << 20));

    const int B = 256;
    if (fastScatter) {
        k_scatter_tile<<<NTILES * KCHUNK, 512, TILE_SIZE * sizeof(float), stream>>>(
            (const float4*)syn_g, (const float4*)syn_w, (const int4*)post_idx, A, S);
        k_neuron<true><<<(N + B - 1) / B, B, 0, stream>>>(ext, Vs, Va, refrac, A,
                                                          spikes, Vs_out, Va_out, N);
    } else {
        const int S4 = S / 4;
        k_zero4<<<(N / 4 + B - 1) / B, B, 0, stream>>>((float4*)A, N / 4);
        k_scatter_gw_dev<<<(S4 + B - 1) / B, B, 0, stream>>>((const float4*)syn_g,
                                                             (const float4*)syn_w,
                                                             (const int4*)post_idx, A, S4);
        k_neuron<false><<<(N + B - 1) / B, B, 0, stream>>>(ext, Vs, Va, refrac, A,
                                                           spikes, Vs_out, Va_out, N);
    }

    if (fastSyn) {
        k_bits<<<N / B, B, 0, stream>>>(spikes, bits, N);
        const int T8 = S / 8;
        k_plast_bits<<<(T8 + B - 1) / B, B, 0, stream>>>(syn_w, pre_trace, post_trace,
                                                         r_pre, r_post, theta_m,
                                                         pre_idx, post_idx, delay, bidx,
                                                         (const unsigned*)bits,
                                                         w_out, prerow, S);
        k_ring_row<<<8 * RING_BPR, B, 0, stream>>>(gbuf, syn_g, prerow, bidx,
                                                   g_out, buf_out, S);
    } else {
        const int T4 = (S + 3) / 4;
        k_syn_update4<<<(T4 + B - 1) / B, B, 0, stream>>>(syn_g, syn_w, pre_trace, post_trace,
                                                          r_pre, r_post, theta_m, gbuf,
                                                          pre_idx, post_idx, delay, bidx,
                                                          spikes, g_out, w_out, buf_out, S, L);
    }
}

// Round 11
// 157.945 us; speedup vs baseline: 1.1483x; 1.1483x over previous
//
#include <hip/hip_runtime.h>
#include <math.h>

// ---- model constants (match reference) ----
#define C_DT_OVER_SOMA  500000.0f      // DT / 2e-10
#define C_DT_OVER_AIS   1000000.0f     // DT / 1e-10
#define C_SOMA_GL       1e-8f
#define C_SOMA_EL       (-0.070f)
#define C_AIS_GL        1e-8f
#define C_AIS_EL        (-0.070f)
#define C_V_T           (-0.050f)
#define C_DELTA_T       0.002f
#define C_V_SPIKE       (-0.030f)
#define C_V_RESET       (-0.065f)
#define C_G_C           5e-9f
#define C_G_MAX         1e-9f
#define C_DECAY_G       0.9801986733067553f   // exp(-DT/0.005)
#define C_DECAY_TR      0.9950124791926823f   // exp(-DT/0.020)
#define C_DECAY_RATE    0.9990004998333751f   // exp(-DT/0.100)
#define C_DT_TAU_THETA  1e-4f
#define C_A_PLUS        0.01f
#define C_A_MINUS       0.012f
#define C_ETA_BCM       1e-4f

#define TILE_BITS   15
#define TILE_SIZE   32768               // neurons per tile (128 KB LDS accumulator)
#define TILE_MASK   (TILE_SIZE - 1)
#define NTILES      8                   // N / TILE_SIZE
#define KCHUNK      32                  // chunk-blocks per tile
#define RING_BPR    256                 // blocks per ring row

typedef float fx4 __attribute__((ext_vector_type(4)));
typedef unsigned char uchar;

__device__ __forceinline__ fx4 nt_load4(const float* p) {
    return __builtin_nontemporal_load((const fx4*)p);
}
__device__ __forceinline__ void nt_store4(float* p, fx4 v) {
    __builtin_nontemporal_store(v, (fx4*)p);
}

__global__ void k_zero4(float4* __restrict__ p, int n4) {
    int i = blockIdx.x * blockDim.x + threadIdx.x;
    if (i < n4) p[i] = make_float4(0.f, 0.f, 0.f, 0.f);
}

// Tiled scatter: block (t,k) accumulates chunk k's synapses targeting tile t
// into a 128 KB LDS accumulator, then writes its partial.
// NOTE (r10): keep t=bid&7 mapping — the t=bid>>5 "XCD-locality" variant
// regressed (dispatch order is undefined; don't lean on it).
__global__ void __launch_bounds__(512, 1)
k_scatter_tile(const float4* __restrict__ g4,
               const float4* __restrict__ w4,
               const int4*   __restrict__ post4,
               float*        __restrict__ partials,   // [NTILES*KCHUNK][TILE_SIZE]
               int S) {
    extern __shared__ float acc[];                    // TILE_SIZE floats
    const int t = blockIdx.x & (NTILES - 1);
    const int k = blockIdx.x >> 3;                    // log2(NTILES)

    for (int i = threadIdx.x; i < TILE_SIZE; i += blockDim.x)
        acc[i] = 0.0f;
    __syncthreads();

    const int cnt4  = (S / KCHUNK) / 4;               // float4 groups per chunk
    const int base4 = k * cnt4;
    for (int j = threadIdx.x; j < cnt4; j += blockDim.x) {
        int4   p = post4[base4 + j];
        float4 g = g4[base4 + j];
        float4 w = w4[base4 + j];
        if ((p.x >> TILE_BITS) == t) atomicAdd(&acc[p.x & TILE_MASK], g.x * w.x);
        if ((p.y >> TILE_BITS) == t) atomicAdd(&acc[p.y & TILE_MASK], g.y * w.y);
        if ((p.z >> TILE_BITS) == t) atomicAdd(&acc[p.z & TILE_MASK], g.z * w.z);
        if ((p.w >> TILE_BITS) == t) atomicAdd(&acc[p.w & TILE_MASK], g.w * w.w);
    }
    __syncthreads();

    float4* dst = (float4*)(partials + (size_t)blockIdx.x * TILE_SIZE);
    const float4* src = (const float4*)acc;
    for (int i = threadIdx.x; i < TILE_SIZE / 4; i += blockDim.x)
        dst[i] = src[i];
}

// neuron step; fast path sums KCHUNK partials for its tile, fallback reads A[i]
template <bool FAST>
__global__ void k_neuron(const float* __restrict__ ext,
                         const float* __restrict__ Vs,
                         const float* __restrict__ Va,
                         const float* __restrict__ refrac,
                         const float* __restrict__ A,
                         float* __restrict__ spikes,
                         float* __restrict__ Vs_out,
                         float* __restrict__ Va_out,
                         int N) {
    int i = blockIdx.x * blockDim.x + threadIdx.x;
    if (i >= N) return;
    float acc = 0.0f;
    if (FAST) {
        const int t = i >> TILE_BITS;
        const int local = i & TILE_MASK;
        const float* base = A + ((size_t)t * KCHUNK) * TILE_SIZE + local;
        #pragma unroll
        for (int k = 0; k < KCHUNK; ++k) acc += base[(size_t)k * TILE_SIZE];
    } else {
        acc = A[i];
    }
    float vs = Vs[i];
    float va = Va[i];
    float I_syn = C_G_MAX * (0.0f - vs) * acc;   // E_REV = 0
    float dvs = C_DT_OVER_SOMA * (-C_SOMA_GL * (vs - C_SOMA_EL) + ext[i]
                                  + I_syn + C_G_C * (va - vs));
    float xarg = fminf((va - C_V_T) / C_DELTA_T, 20.0f);
    float exp_term = C_AIS_GL * C_DELTA_T * expf(xarg);
    float dva = C_DT_OVER_AIS * (-C_AIS_GL * (va - C_AIS_EL) + exp_term
                                 + C_G_C * (vs - va));
    float vs_new = vs + dvs;
    float va_new = (0.0f < refrac[i]) ? C_V_RESET : (va + dva);
    float hard = (va_new >= C_V_SPIKE) ? 1.0f : 0.0f;
    float va_out = (hard > 0.0f) ? C_V_RESET : va_new;
    spikes[i] = hard;          // gathered next -> keep cacheable
    __builtin_nontemporal_store(vs_new, &Vs_out[i]);
    __builtin_nontemporal_store(va_out, &Va_out[i]);
}

// pack spikes into a 32 KB bitmask (L1/L2-resident -> cheap gathers in plast)
__global__ void k_bits(const float* __restrict__ spikes,
                       unsigned long long* __restrict__ bits,
                       int N) {
    int i = blockIdx.x * blockDim.x + threadIdx.x;
    if (i >= N) return;
    float s = spikes[i];
    unsigned long long m = __ballot(s > 0.5f);
    if ((threadIdx.x & 63) == 0) bits[i >> 6] = m;
}

// fallback scatter (device-scope HW fp atomics)
__global__ void k_scatter_gw_dev(const float4* __restrict__ g4,
                                 const float4* __restrict__ w4,
                                 const int4*   __restrict__ post4,
                                 float*        __restrict__ A,
                                 int S4) {
    int t = blockIdx.x * blockDim.x + threadIdx.x;
    if (t >= S4) return;
    float4 g = g4[t];
    float4 w = w4[t];
    int4   p = post4[t];
    unsafeAtomicAdd(&A[p.x], g.x * w.x);
    unsafeAtomicAdd(&A[p.y], g.y * w.y);
    unsafeAtomicAdd(&A[p.z], g.z * w.z);
    unsafeAtomicAdd(&A[p.w], g.w * w.w);
}

__device__ __forceinline__ float bit_gather(const unsigned* __restrict__ bits32, int idx) {
    return (float)((bits32[idx >> 5] >> (idx & 31)) & 1u);
}

// plasticity (STDP + BCM -> w_out) + prerow side-array; spike gathers via
// global 32 KB bitmask (L1-hot); params via regular cached loads — they are
// L3-resident ACROSS graph replays (nt loads here regressed in r10).
__global__ void k_plast_bits(const float* __restrict__ syn_w,
                             const float* __restrict__ pre_trace,
                             const float* __restrict__ post_trace,
                             const float* __restrict__ r_pre,
                             const float* __restrict__ r_post,
                             const float* __restrict__ theta_m,
                             const int*   __restrict__ pre_idx,
                             const int*   __restrict__ post_idx,
                             const int*   __restrict__ delay,
                             const int*   __restrict__ bidx_p,
                             const unsigned* __restrict__ bits32,
                             float* __restrict__ w_out,
                             uchar* __restrict__ prerow,
                             int S) {
    int t = blockIdx.x * blockDim.x + threadIdx.x;
    int j = t * 8;
    if (j >= S) return;
    const int bidx = bidx_p[0];

    int4 pi0 = *(const int4*)(pre_idx + j);
    int4 pi1 = *(const int4*)(pre_idx + j + 4);
    int4 qi0 = *(const int4*)(post_idx + j);
    int4 qi1 = *(const int4*)(post_idx + j + 4);
    int4 dl0 = *(const int4*)(delay + j);
    int4 dl1 = *(const int4*)(delay + j + 4);

    float pre[8], post[8];
    pre[0] = bit_gather(bits32, pi0.x); pre[1] = bit_gather(bits32, pi0.y);
    pre[2] = bit_gather(bits32, pi0.z); pre[3] = bit_gather(bits32, pi0.w);
    pre[4] = bit_gather(bits32, pi1.x); pre[5] = bit_gather(bits32, pi1.y);
    pre[6] = bit_gather(bits32, pi1.z); pre[7] = bit_gather(bits32, pi1.w);
    post[0] = bit_gather(bits32, qi0.x); post[1] = bit_gather(bits32, qi0.y);
    post[2] = bit_gather(bits32, qi0.z); post[3] = bit_gather(bits32, qi0.w);
    post[4] = bit_gather(bits32, qi1.x); post[5] = bit_gather(bits32, qi1.y);
    post[6] = bit_gather(bits32, qi1.z); post[7] = bit_gather(bits32, qi1.w);

    float4 w0  = *(const float4*)(syn_w + j);
    float4 w1  = *(const float4*)(syn_w + j + 4);
    float4 pt0 = *(const float4*)(pre_trace + j);
    float4 pt1 = *(const float4*)(pre_trace + j + 4);
    float4 qt0 = *(const float4*)(post_trace + j);
    float4 qt1 = *(const float4*)(post_trace + j + 4);
    float4 rp0 = *(const float4*)(r_pre + j);
    float4 rp1 = *(const float4*)(r_pre + j + 4);
    float4 rq0 = *(const float4*)(r_post + j);
    float4 rq1 = *(const float4*)(r_post + j + 4);
    float4 th0 = *(const float4*)(theta_m + j);
    float4 th1 = *(const float4*)(theta_m + j + 4);

    float wv[8]  = {w0.x, w0.y, w0.z, w0.w, w1.x, w1.y, w1.z, w1.w};
    float ptv[8] = {pt0.x, pt0.y, pt0.z, pt0.w, pt1.x, pt1.y, pt1.z, pt1.w};
    float qtv[8] = {qt0.x, qt0.y, qt0.z, qt0.w, qt1.x, qt1.y, qt1.z, qt1.w};
    float rpv[8] = {rp0.x, rp0.y, rp0.z, rp0.w, rp1.x, rp1.y, rp1.z, rp1.w};
    float rqv[8] = {rq0.x, rq0.y, rq0.z, rq0.w, rq1.x, rq1.y, rq1.z, rq1.w};
    float thv[8] = {th0.x, th0.y, th0.z, th0.w, th1.x, th1.y, th1.z, th1.w};
    int   dlv[8] = {dl0.x, dl0.y, dl0.z, dl0.w, dl1.x, dl1.y, dl1.z, dl1.w};

    float wo[8];
    unsigned prw[8];
    #pragma unroll
    for (int k = 0; k < 8; ++k) {
        float ptr_n = ptv[k] * C_DECAY_TR + pre[k];
        float qtr_n = qtv[k] * C_DECAY_TR + post[k];
        float dw_stdp = C_A_PLUS * ptr_n * post[k] - C_A_MINUS * qtr_n * pre[k];
        float rpn = rpv[k] * C_DECAY_RATE + pre[k];
        float rqn = rqv[k] * C_DECAY_RATE + post[k];
        float thn = thv[k] + C_DT_TAU_THETA * (rqn * rqn - thv[k]);
        float dw_bcm = C_ETA_BCM * rpn * rqn * (rqn - thn);
        float wn = wv[k] + dw_stdp + dw_bcm;
        wo[k] = fminf(fmaxf(wn, 0.0f), 1.0f);
        prw[k] = (pre[k] > 0.5f) ? (unsigned)(((bidx + dlv[k]) & 7) + 1) : 0u;
    }
    fx4 a = {wo[0], wo[1], wo[2], wo[3]};
    fx4 b = {wo[4], wo[5], wo[6], wo[7]};
    nt_store4(w_out + j, a);
    nt_store4(w_out + j + 4, b);

    uint2 packed;
    packed.x = prw[0] | (prw[1] << 8) | (prw[2] << 16) | (prw[3] << 24);
    packed.y = prw[4] | (prw[5] << 8) | (prw[6] << 16) | (prw[7] << 24);
    *(uint2*)(prerow + j) = packed;     // cacheable: re-read 8x by ring pass
}

// ring pass, lane-contiguous: 8 rows x RING_BPR blocks; one float4 per thread
// per iteration (1 KB contiguous per wave instruction).
__global__ void k_ring_row(const float* __restrict__ gbuf,
                           const float* __restrict__ syn_g,
                           const uchar* __restrict__ prerow,
                           const int*   __restrict__ bidx_p,
                           float* __restrict__ g_out,
                           float* __restrict__ buf_out,
                           int S) {
    const int bidx = bidx_p[0];
    const int row  = blockIdx.x / RING_BPR;
    const int blk  = blockIdx.x - row * RING_BPR;
    const int span = S / RING_BPR;
    const int base = blk * span;
    const float* src = gbuf + (size_t)row * (size_t)S;
    float*       dst = buf_out + (size_t)row * (size_t)S;
    const unsigned target = (unsigned)(row + 1);
    const int step = blockDim.x * 4;

    if (row == bidx) {
        for (int off = threadIdx.x * 4; off < span; off += step) {
            const int j = base + off;
            fx4 v  = nt_load4(src + j);
            fx4 sg = *(const fx4*)(syn_g + j);
            fx4 go = sg * (float)C_DECAY_G + v;
            nt_store4(g_out + j, go);
            unsigned wd = *(const unsigned*)(prerow + j);
            fx4 z;
            z.x = ((wd        & 255u) == target) ? 1.0f : 0.0f;
            z.y = (((wd >> 8)  & 255u) == target) ? 1.0f : 0.0f;
            z.z = (((wd >> 16) & 255u) == target) ? 1.0f : 0.0f;
            z.w = (((wd >> 24)       ) == target) ? 1.0f : 0.0f;
            nt_store4(dst + j, z);
        }
    } else {
        for (int off = threadIdx.x * 4; off < span; off += step) {
            const int j = base + off;
            fx4 v = nt_load4(src + j);
            unsigned wd = *(const unsigned*)(prerow + j);
            v.x += ((wd        & 255u) == target) ? 1.0f : 0.0f;
            v.y += (((wd >> 8)  & 255u) == target) ? 1.0f : 0.0f;
            v.z += (((wd >> 16) & 255u) == target) ? 1.0f : 0.0f;
            v.w += (((wd >> 24)       ) == target) ? 1.0f : 0.0f;
            nt_store4(dst + j, v);
        }
    }
}

// fallback fused per-synapse update (arbitrary L)
__global__ void k_syn_update4(const float* __restrict__ syn_g,
                              const float* __restrict__ syn_w,
                              const float* __restrict__ pre_trace,
                              const float* __restrict__ post_trace,
                              const float* __restrict__ r_pre,
                              const float* __restrict__ r_post,
                              const float* __restrict__ theta_m,
                              const float* __restrict__ gbuf,
                              const int*   __restrict__ pre_idx,
                              const int*   __restrict__ post_idx,
                              const int*   __restrict__ delay,
                              const int*   __restrict__ bidx_p,
                              const float* __restrict__ spikes,
                              float* __restrict__ g_out,
                              float* __restrict__ w_out,
                              float* __restrict__ buf_out,
                              int S, int L) {
    int t = blockIdx.x * blockDim.x + threadIdx.x;
    int j = t * 4;
    if (j >= S) return;
    const int bidx = bidx_p[0];
    int4 pi = *(const int4*)(pre_idx + j);
    int4 qi = *(const int4*)(post_idx + j);
    int4 dl = *(const int4*)(delay + j);
    float pre[4], post[4];
    pre[0] = spikes[pi.x]; pre[1] = spikes[pi.y]; pre[2] = spikes[pi.z]; pre[3] = spikes[pi.w];
    post[0] = spikes[qi.x]; post[1] = spikes[qi.y]; post[2] = spikes[qi.z]; post[3] = spikes[qi.w];
    float4 g  = *(const float4*)(syn_g + j);
    float4 w  = *(const float4*)(syn_w + j);
    float4 pt = *(const float4*)(pre_trace + j);
    float4 qt = *(const float4*)(post_trace + j);
    float4 rp = *(const float4*)(r_pre + j);
    float4 rq = *(const float4*)(r_post + j);
    float4 th = *(const float4*)(theta_m + j);
    float wv[4]  = {w.x, w.y, w.z, w.w};
    float ptv[4] = {pt.x, pt.y, pt.z, pt.w};
    float qtv[4] = {qt.x, qt.y, qt.z, qt.w};
    float rpv[4] = {rp.x, rp.y, rp.z, rp.w};
    float rqv[4] = {rq.x, rq.y, rq.z, rq.w};
    float thv[4] = {th.x, th.y, th.z, th.w};
    float wo[4];
    #pragma unroll
    for (int k = 0; k < 4; ++k) {
        float ptr_n = ptv[k] * C_DECAY_TR + pre[k];
        float qtr_n = qtv[k] * C_DECAY_TR + post[k];
        float dw_stdp = C_A_PLUS * ptr_n * post[k] - C_A_MINUS * qtr_n * pre[k];
        float rpn = rpv[k] * C_DECAY_RATE + pre[k];
        float rqn = rqv[k] * C_DECAY_RATE + post[k];
        float thn = thv[k] + C_DT_TAU_THETA * (rqn * rqn - thv[k]);
        float dw_bcm = C_ETA_BCM * rpn * rqn * (rqn - thn);
        float wn = wv[k] + dw_stdp + dw_bcm;
        wo[k] = fminf(fmaxf(wn, 0.0f), 1.0f);
    }
    float4 wo4 = {wo[0], wo[1], wo[2], wo[3]};
    *(float4*)(w_out + j) = wo4;
    int row[4];
    row[0] = (bidx + dl.x) % L;
    row[1] = (bidx + dl.y) % L;
    row[2] = (bidx + dl.z) % L;
    row[3] = (bidx + dl.w) % L;
    float gv[4] = {g.x, g.y, g.z, g.w};
    for (int r = 0; r < L; ++r) {
        float4 v = *(const float4*)(gbuf + (size_t)r * (size_t)S + j);
        float vv[4] = {v.x, v.y, v.z, v.w};
        if (r == bidx) {
            float4 gn;
            gn.x = gv[0] * C_DECAY_G + vv[0];
            gn.y = gv[1] * C_DECAY_G + vv[1];
            gn.z = gv[2] * C_DECAY_G + vv[2];
            gn.w = gv[3] * C_DECAY_G + vv[3];
            *(float4*)(g_out + j) = gn;
            vv[0] = vv[1] = vv[2] = vv[3] = 0.0f;
        }
        #pragma unroll
        for (int k = 0; k < 4; ++k)
            if (r == row[k]) vv[k] += pre[k];
        float4 ov = {vv[0], vv[1], vv[2], vv[3]};
        *(float4*)(buf_out + (size_t)r * (size_t)S + j) = ov;
    }
}

extern "C" void kernel_launch(void* const* d_in, const int* in_sizes, int n_in,
                              void* d_out, int out_size, void* d_ws, size_t ws_size,
                              hipStream_t stream) {
    const int N = in_sizes[0];
    const int S = in_sizes[1];
    const int L = in_sizes[11] / S;

    const float* ext        = (const float*)d_in[0];
    const float* syn_w      = (const float*)d_in[1];
    const float* Vs         = (const float*)d_in[2];
    const float* Va         = (const float*)d_in[3];
    const float* refrac     = (const float*)d_in[4];
    const float* syn_g      = (const float*)d_in[5];
    const float* pre_trace  = (const float*)d_in[6];
    const float* post_trace = (const float*)d_in[7];
    const float* r_pre      = (const float*)d_in[8];
    const float* r_post     = (const float*)d_in[9];
    const float* theta_m    = (const float*)d_in[10];
    const float* gbuf       = (const float*)d_in[11];
    const int*   pre_idx    = (const int*)d_in[12];
    const int*   post_idx   = (const int*)d_in[13];
    const int*   delay      = (const int*)d_in[14];
    const int*   bidx       = (const int*)d_in[15];

    float* out     = (float*)d_out;
    float* spikes  = out;
    float* Vs_out  = out + (size_t)N;
    float* Va_out  = out + (size_t)2 * N;
    float* g_out   = out + (size_t)3 * N;
    float* w_out   = out + (size_t)3 * N + (size_t)S;
    float* buf_out = out + (size_t)3 * N + (size_t)2 * S;

    // ws layout: A partials [0, 32MB); prerow aliases A[0, S) (written after A
    // is dead); bits alias A at +8MB (written after A is dead, clear of prerow).
    float* A = (float*)d_ws;
    uchar* prerow = (uchar*)d_ws;
    unsigned long long* bits = (unsigned long long*)((char*)d_ws + ((size_t)8 << 20));

    const size_t need = (size_t)NTILES * KCHUNK * TILE_SIZE * sizeof(float);
    const bool fastScatter = (N == NTILES * TILE_SIZE) &&
                             (S % (KCHUNK * 4) == 0) &&
                             (ws_size >= need);
    const bool fastSyn = fastScatter && (L == 8) && (S % (RING_BPR * 256 * 4) == 0) &&
                         (S % 8 == 0) && (N % 256 == 0) &&
                         (((size_t)8 << 20) + N / 8 <= ws_size) && ((size_t)S <= ((size_t)8 << 20));

    const int B = 256;
    if (fastScatter) {
        k_scatter_tile<<<NTILES * KCHUNK, 512, TILE_SIZE * sizeof(float), stream>>>(
            (const float4*)syn_g, (const float4*)syn_w, (const int4*)post_idx, A, S);
        k_neuron<true><<<(N + B - 1) / B, B, 0, stream>>>(ext, Vs, Va, refrac, A,
                                                          spikes, Vs_out, Va_out, N);
    } else {
        const int S4 = S / 4;
        k_zero4<<<(N / 4 + B - 1) / B, B, 0, stream>>>((float4*)A, N / 4);
        k_scatter_gw_dev<<<(S4 + B - 1) / B, B, 0, stream>>>((const float4*)syn_g,
                                                             (const float4*)syn_w,
                                                             (const int4*)post_idx, A, S4);
        k_neuron<false><<<(N + B - 1) / B, B, 0, stream>>>(ext, Vs, Va, refrac, A,
                                                           spikes, Vs_out, Va_out, N);
    }

    if (fastSyn) {
        k_bits<<<N / B, B, 0, stream>>>(spikes, bits, N);
        const int T8 = S / 8;
        k_plast_bits<<<(T8 + B - 1) / B, B, 0, stream>>>(syn_w, pre_trace, post_trace,
                                                         r_pre, r_post, theta_m,
                                                         pre_idx, post_idx, delay, bidx,
                                                         (const unsigned*)bits,
                                                         w_out, prerow, S);
        k_ring_row<<<8 * RING_BPR, B, 0, stream>>>(gbuf, syn_g, prerow, bidx,
                                                   g_out, buf_out, S);
    } else {
        const int T4 = (S + 3) / 4;
        k_syn_update4<<<(T4 + B - 1) / B, B, 0, stream>>>(syn_g, syn_w, pre_trace, post_trace,
                                                          r_pre, r_post, theta_m, gbuf,
                                                          pre_idx, post_idx, delay, bidx,
                                                          spikes, g_out, w_out, buf_out, S, L);
    }
}